// Round 11
// baseline (184.056 us; speedup 1.0000x reference)
//
#include <hip/hip_runtime.h>

#define HD 10
#define C2 20
#define PIX (192*192)
#define NB 8
#define NPIX (NB*PIX)
#define CHW (NB*HD*PIX)
#define EPSB 1e-5f
#define BPB (PIX/256)        // blocks per (batch,half) image = 144

// LDS layout (floats): BN-folded weights + biases for this block's half
#define DW1o 0
#define DB1o 400
#define DW2o 420
#define DB2o 620
#define CW1o 630
#define CB1o 1030
#define CW2o 1050
#define CB2o 1250
#define WGo  1260
#define BGo  1660
#define WCo  1680
#define BCo  1880
#define SWTOT 1890

__device__ __forceinline__ float rsq_fast(float x) {
    return __builtin_amdgcn_rsqf(x);
}
__device__ __forceinline__ float sigm(float x) {
    return __builtin_amdgcn_rcpf(1.0f + __expf(-x));
}
__device__ __forceinline__ float tanh_fast(float x) {
    return 1.0f - 2.0f * __builtin_amdgcn_rcpf(1.0f + __expf(2.0f * x));
}

// r7 compute structure, but weights come from LDS (ds_read broadcast) instead of
// the SGPR s_load stream — r10 eliminated every other stall candidate; SGPR=112
// (hard budget) was pegged in every round. BN folded into weights at staging:
// per-pixel BN math gone. 7.6 KB LDS/block, staged once per block lifetime.
__global__ __launch_bounds__(256) void half_kernel(
    const float* __restrict__ xf, const float* __restrict__ xh, const float* __restrict__ xp,
    const float* __restrict__ h_att, const float* __restrict__ p_att,
    const float* __restrict__ dW1, const float* __restrict__ dbn1,
    const float* __restrict__ dW2, const float* __restrict__ dbn2,
    const float* __restrict__ uW1, const float* __restrict__ ubn1,
    const float* __restrict__ uW2, const float* __restrict__ ubn2,
    const float* __restrict__ lW1, const float* __restrict__ lbn1,
    const float* __restrict__ lW2, const float* __restrict__ lbn2,
    const float* __restrict__ guWg, const float* __restrict__ gubg,
    const float* __restrict__ guWc, const float* __restrict__ gubc,
    const float* __restrict__ glWg, const float* __restrict__ glbg,
    const float* __restrict__ glWc, const float* __restrict__ glbc,
    float* __restrict__ out)
{
    __shared__ float sw[SWTOT];

    const int bid  = blockIdx.x;
    const int half = bid & 1;                    // interleaved for load balance
    const int bx   = bid >> 1;
    const int b    = bx / BPB;                   // uniform per block
    const int s    = (bx - b * BPB) * 256 + threadIdx.x;
    const int base  = b * (HD*PIX) + s;          // [B,HD,P] tensors: + c*PIX
    const int abase = b * PIX + s;               // [*,B,1,P] attention maps
    const int tid = threadIdx.x;

    // half-specific raw pointers (wave-uniform)
    const float* Wc1  = half ? lW1  : uW1;
    const float* cbn1 = half ? lbn1 : ubn1;
    const float* Wc2  = half ? lW2  : uW2;
    const float* cbn2 = half ? lbn2 : ubn2;
    const float* Wg = half ? glWg : guWg;
    const float* bg = half ? glbg : gubg;
    const float* Wc = half ? glWc : guWc;
    const float* bc = half ? glbc : gubc;

    // ---- stage BN-folded weights into LDS (once per block) ----
    for (int i = tid; i < 400; i += 256) {
        int row = i / C2;
        sw[DW1o + i] = dW1[i] * (dbn1[row] * rsq_fast(dbn1[3*C2 + row] + EPSB));
        sw[CW1o + i] = Wc1[i] * (cbn1[row] * rsq_fast(cbn1[3*C2 + row] + EPSB));
        sw[WGo  + i] = Wg[i];
    }
    for (int i = tid; i < 200; i += 256) {
        int row = i / C2;
        sw[DW2o + i] = dW2[i] * (dbn2[row] * rsq_fast(dbn2[3*HD + row] + EPSB));
        sw[CW2o + i] = Wc2[i] * (cbn2[row] * rsq_fast(cbn2[3*HD + row] + EPSB));
        sw[WCo  + i] = Wc[i];
    }
    if (tid < C2) {
        float sc = dbn1[tid] * rsq_fast(dbn1[3*C2 + tid] + EPSB);
        sw[DB1o + tid] = dbn1[C2 + tid] - sc * dbn1[2*C2 + tid];
        float s1 = cbn1[tid] * rsq_fast(cbn1[3*C2 + tid] + EPSB);
        sw[CB1o + tid] = cbn1[C2 + tid] - s1 * cbn1[2*C2 + tid];
        sw[BGo + tid] = bg[tid];
    } else if (tid >= 32 && tid < 32 + HD) {
        int o = tid - 32;
        float sc = dbn2[o] * rsq_fast(dbn2[3*HD + o] + EPSB);
        sw[DB2o + o] = dbn2[HD + o] - sc * dbn2[2*HD + o];
        float s2 = cbn2[o] * rsq_fast(cbn2[3*HD + o] + EPSB);
        sw[CB2o + o] = cbn2[HD + o] - s2 * cbn2[2*HD + o];
        sw[BCo + o] = bc[o];
    }
    __syncthreads();

    const float* xhh = xh + half * CHW;
    float* outh = out + half * CHW;

    float vxh[HD];
    #pragma unroll
    for (int c = 0; c < HD; ++c) vxh[c] = xhh[base + c*PIX];

    const float ha = h_att[(1 + half) * NPIX + abase];
    float catt = 0.f;
    {
        const int mstart = half ? 5 : 1;
        const int natt   = half ? 2 : 4;
        #pragma unroll
        for (int j = 0; j < 4; ++j)
            if (j < natt) catt += p_att[(mstart + j) * NPIX + abase];
    }

    // ---- decomposition block -> message accumulator m ----
    float m[HD];
    {
        float xfha[HD];
        #pragma unroll
        for (int c = 0; c < HD; ++c) xfha[c] = xf[base + c*PIX] * ha;
        float h[C2];
        #pragma unroll
        for (int o = 0; o < C2; ++o) {
            float a = sw[DB1o + o];
            #pragma unroll
            for (int k = 0; k < HD; ++k) a = fmaf(sw[DW1o + o*C2 + k], xfha[k], a);
            #pragma unroll
            for (int k = 0; k < HD; ++k) a = fmaf(sw[DW1o + o*C2 + HD + k], vxh[k], a);
            h[o] = fmaxf(a, 0.f);
        }
        #pragma unroll
        for (int o = 0; o < HD; ++o) {
            float a = sw[DB2o + o];
            #pragma unroll
            for (int k = 0; k < C2; ++k) a = fmaf(sw[DW2o + o*C2 + k], h[k], a);
            m[o] = fmaxf(a, 0.f);
        }
    }

    // ---- composition blocks (part loop statically unrolled, uniform guards) ----
    {
        // pre[] = folded conv1 applied to the shared xh-half (bias included)
        float pre[C2];
        #pragma unroll
        for (int o = 0; o < C2; ++o) {
            float a = sw[CB1o + o];
            #pragma unroll
            for (int k = 0; k < HD; ++k) a = fmaf(sw[CW1o + o*C2 + k], vxh[k], a);
            pre[o] = a;
        }
        const int pstart = half ? 4 : 0;
        const int nparts = half ? 2 : 4;
        #pragma unroll
        for (int i = 0; i < 4; ++i) {
            if (i < nparts) {                    // wave-uniform guard
                float xpi[HD];                   // raw loads; catt applied at use
                #pragma unroll
                for (int c = 0; c < HD; ++c)
                    xpi[c] = xp[(pstart + i) * CHW + base + c*PIX];
                float h[C2];
                #pragma unroll
                for (int o = 0; o < C2; ++o) {
                    float a = 0.f;
                    #pragma unroll
                    for (int k = 0; k < HD; ++k) a = fmaf(sw[CW1o + o*C2 + HD + k], xpi[k], a);
                    h[o] = fmaxf(fmaf(a, catt, pre[o]), 0.f);
                }
                #pragma unroll
                for (int o = 0; o < HD; ++o) {
                    float a = sw[CB2o + o];
                    #pragma unroll
                    for (int k = 0; k < C2; ++k) a = fmaf(sw[CW2o + o*C2 + k], h[k], a);
                    m[o] += fmaxf(a, 0.f);
                }
            }
        }
    }

    // ---- GRU ----
    float g[C2];
    #pragma unroll
    for (int o = 0; o < C2; ++o) {
        float a = sw[BGo + o];
        #pragma unroll
        for (int k = 0; k < HD; ++k) a = fmaf(sw[WGo + o*C2 + k], m[k], a);
        #pragma unroll
        for (int k = 0; k < HD; ++k) a = fmaf(sw[WGo + o*C2 + HD + k], vxh[k], a);
        g[o] = sigm(a);
    }
    float rh[HD];
    #pragma unroll
    for (int k = 0; k < HD; ++k) rh[k] = g[k] * vxh[k];
    #pragma unroll
    for (int o = 0; o < HD; ++o) {
        float a = sw[BCo + o];
        #pragma unroll
        for (int k = 0; k < HD; ++k) a = fmaf(sw[WCo + o*C2 + k], m[k], a);
        #pragma unroll
        for (int k = 0; k < HD; ++k) a = fmaf(sw[WCo + o*C2 + HD + k], rh[k], a);
        float c = tanh_fast(a);
        float u = g[HD + o];
        outh[base + o*PIX] = fmaf(u, c - vxh[o], vxh[o]);   // (1-u)*h + u*c
    }
}

extern "C" void kernel_launch(void* const* d_in, const int* in_sizes, int n_in,
                              void* d_out, int out_size, void* d_ws, size_t ws_size,
                              hipStream_t stream) {
    const float* xf    = (const float*)d_in[0];
    const float* xh    = (const float*)d_in[1];
    const float* xp    = (const float*)d_in[2];
    const float* h_att = (const float*)d_in[3];
    const float* p_att = (const float*)d_in[4];
    const float* dW1   = (const float*)d_in[5];
    const float* dbn1  = (const float*)d_in[6];
    const float* dW2   = (const float*)d_in[7];
    const float* dbn2  = (const float*)d_in[8];
    const float* uW1   = (const float*)d_in[9];
    const float* ubn1  = (const float*)d_in[10];
    const float* uW2   = (const float*)d_in[11];
    const float* ubn2  = (const float*)d_in[12];
    const float* lW1   = (const float*)d_in[13];
    const float* lbn1  = (const float*)d_in[14];
    const float* lW2   = (const float*)d_in[15];
    const float* lbn2  = (const float*)d_in[16];
    const float* guWg  = (const float*)d_in[17];
    const float* gubg  = (const float*)d_in[18];
    const float* guWc  = (const float*)d_in[19];
    const float* gubc  = (const float*)d_in[20];
    const float* glWg  = (const float*)d_in[21];
    const float* glbg  = (const float*)d_in[22];
    const float* glWc  = (const float*)d_in[23];
    const float* glbc  = (const float*)d_in[24];

    dim3 grid((NPIX / 256) * 2), block(256);
    half_kernel<<<grid, block, 0, stream>>>(
        xf, xh, xp, h_att, p_att,
        dW1, dbn1, dW2, dbn2,
        uW1, ubn1, uW2, ubn2,
        lW1, lbn1, lW2, lbn2,
        guWg, gubg, guWc, gubc,
        glWg, glbg, glWc, glbc,
        (float*)d_out);
}

// Round 12
// 136.351 us; speedup vs baseline: 1.3499x; 1.3499x over previous
//
#include <hip/hip_runtime.h>

#define HD 10
#define C2 20
#define PIX (192*192)
#define NB 8
#define NPIX (NB*PIX)
#define CHW (NB*HD*PIX)
#define EPSB 1e-5f
#define BPB (PIX/256)        // blocks per (batch,half) image = 144
#define NBLK ((NPIX/256)*2)  // 2304 blocks
#define SLICE 1024           // dwords per block slice (990 used, 4KB stride)

// packed-weight slice layout (dword offsets)
#define DW1 0      // 20x10 packed f16x2 (BN-folded)
#define DW2 200    // 10x10
#define CW1 300    // 20x10  (cols 0-9=xh pairs j<5, cols 10-19=xp pairs j>=5)
#define CW2 500    // 10x10
#define WGo 600    // 20x10  (cols 0-9=m, 10-19=h)
#define WCo 800    // 10x10  (cols 0-9=m, 10-19=rh)
#define DB1 900
#define DB2 920
#define CB1 930
#define CB2 950
#define BGo 960
#define BCo 980
#define USED 990

typedef _Float16 half2_t __attribute__((ext_vector_type(2)));
typedef unsigned int uint;

__device__ __forceinline__ float rsq_fast(float x) { return __builtin_amdgcn_rsqf(x); }
__device__ __forceinline__ float sigm(float x) {
    return __builtin_amdgcn_rcpf(1.0f + __expf(-x));
}
__device__ __forceinline__ float tanh_fast(float x) {
    return 1.0f - 2.0f * __builtin_amdgcn_rcpf(1.0f + __expf(2.0f * x));
}
__device__ __forceinline__ uint pk(float a, float b) {
    return __builtin_bit_cast(uint, __builtin_amdgcn_cvt_pkrtz(a, b));
}
__device__ __forceinline__ float dot2(uint w, half2_t a, float acc) {
    return __builtin_amdgcn_fdot2(__builtin_bit_cast(half2_t, w), a, acc, false);
}

// f16-dot2 kernel: per-block private ws slice holds BN-folded f16x2-packed weights
// (packed in-kernel, no cross-block/kernel dataflow). Weights stream via s_load as
// before but HALF the dwords; conv FMAs halved via v_dot2_f32_f16 (2 MAC/instr).
__global__ __launch_bounds__(256) void half_kernel_f16(
    const float* __restrict__ xf, const float* __restrict__ xh, const float* __restrict__ xp,
    const float* __restrict__ h_att, const float* __restrict__ p_att,
    const float* __restrict__ dW1p, const float* __restrict__ dbn1,
    const float* __restrict__ dW2p, const float* __restrict__ dbn2,
    const float* __restrict__ uW1, const float* __restrict__ ubn1,
    const float* __restrict__ uW2, const float* __restrict__ ubn2,
    const float* __restrict__ lW1, const float* __restrict__ lbn1,
    const float* __restrict__ lW2, const float* __restrict__ lbn2,
    const float* __restrict__ guWg, const float* __restrict__ gubg,
    const float* __restrict__ guWc, const float* __restrict__ gubc,
    const float* __restrict__ glWg, const float* __restrict__ glbg,
    const float* __restrict__ glWc, const float* __restrict__ glbc,
    uint* __restrict__ wsw, float* __restrict__ out)
{
    const int bid  = blockIdx.x;
    const int half = bid & 1;                    // interleaved for load balance
    const int bx   = bid >> 1;
    const int b    = bx / BPB;                   // uniform per block
    const int s    = (bx - b * BPB) * 256 + threadIdx.x;
    const int base  = b * (HD*PIX) + s;
    const int abase = b * PIX + s;
    const int tid = threadIdx.x;

    const float* Wc1  = half ? lW1  : uW1;
    const float* cbn1 = half ? lbn1 : ubn1;
    const float* Wc2  = half ? lW2  : uW2;
    const float* cbn2 = half ? lbn2 : ubn2;
    const float* Wg = half ? glWg : guWg;
    const float* bg = half ? glbg : gubg;
    const float* Wc = half ? glWc : guWc;
    const float* bc = half ? glbc : gubc;

    // ---- phase A: pack BN-folded weights into this block's PRIVATE slice ----
    uint* sl = wsw + bid * SLICE;
    for (int idx = tid; idx < USED; idx += 256) {
        if (idx < 900) {                          // packed f16 pair entries
            float v0, v1;
            if (idx < 200) {
                int j = idx, row = j / 10, kk = 2 * (j - row * 10);
                float sc = dbn1[row] * rsq_fast(dbn1[3*C2 + row] + EPSB);
                v0 = dW1p[row*C2 + kk] * sc;  v1 = dW1p[row*C2 + kk + 1] * sc;
            } else if (idx < 300) {
                int j = idx - 200, row = j / 10, kk = 2 * (j - row * 10);
                float sc = dbn2[row] * rsq_fast(dbn2[3*HD + row] + EPSB);
                v0 = dW2p[row*C2 + kk] * sc;  v1 = dW2p[row*C2 + kk + 1] * sc;
            } else if (idx < 500) {
                int j = idx - 300, row = j / 10, kk = 2 * (j - row * 10);
                float sc = cbn1[row] * rsq_fast(cbn1[3*C2 + row] + EPSB);
                v0 = Wc1[row*C2 + kk] * sc;   v1 = Wc1[row*C2 + kk + 1] * sc;
            } else if (idx < 600) {
                int j = idx - 500, row = j / 10, kk = 2 * (j - row * 10);
                float sc = cbn2[row] * rsq_fast(cbn2[3*HD + row] + EPSB);
                v0 = Wc2[row*C2 + kk] * sc;   v1 = Wc2[row*C2 + kk + 1] * sc;
            } else if (idx < 800) {
                int j = idx - 600, row = j / 10, kk = 2 * (j - row * 10);
                v0 = Wg[row*C2 + kk];         v1 = Wg[row*C2 + kk + 1];
            } else {
                int j = idx - 800, row = j / 10, kk = 2 * (j - row * 10);
                v0 = Wc[row*C2 + kk];         v1 = Wc[row*C2 + kk + 1];
            }
            sl[idx] = pk(v0, v1);
        } else {                                  // f32 bias entries
            float bv;
            if (idx < 920) {
                int o = idx - 900;
                float sc = dbn1[o] * rsq_fast(dbn1[3*C2 + o] + EPSB);
                bv = dbn1[C2 + o] - sc * dbn1[2*C2 + o];
            } else if (idx < 930) {
                int o = idx - 920;
                float sc = dbn2[o] * rsq_fast(dbn2[3*HD + o] + EPSB);
                bv = dbn2[HD + o] - sc * dbn2[2*HD + o];
            } else if (idx < 950) {
                int o = idx - 930;
                float sc = cbn1[o] * rsq_fast(cbn1[3*C2 + o] + EPSB);
                bv = cbn1[C2 + o] - sc * cbn1[2*C2 + o];
            } else if (idx < 960) {
                int o = idx - 950;
                float sc = cbn2[o] * rsq_fast(cbn2[3*HD + o] + EPSB);
                bv = cbn2[HD + o] - sc * cbn2[2*HD + o];
            } else if (idx < 980) {
                bv = bg[idx - 960];
            } else {
                bv = bc[idx - 980];
            }
            sl[idx] = __builtin_bit_cast(uint, bv);
        }
    }
    __syncthreads();    // drains vmcnt: slice visible in this XCD's L2 before s_loads

    const uint*  wsl = sl;                        // wave-uniform -> s_load stream
    const float* wsf = (const float*)sl;

    const float* xhh = xh + half * CHW;
    float* outh = out + half * CHW;

    // ---- phase B: per-pixel compute ----
    float vxh[HD];
    #pragma unroll
    for (int c = 0; c < HD; ++c) vxh[c] = xhh[base + c*PIX];
    half2_t axh[5];
    #pragma unroll
    for (int j = 0; j < 5; ++j)
        axh[j] = __builtin_bit_cast(half2_t, pk(vxh[2*j], vxh[2*j+1]));

    const float ha = h_att[(1 + half) * NPIX + abase];
    float catt = 0.f;
    {
        const int mstart = half ? 5 : 1;
        const int natt   = half ? 2 : 4;
        #pragma unroll
        for (int j = 0; j < 4; ++j)
            if (j < natt) catt += p_att[(mstart + j) * NPIX + abase];
    }

    // ---- decomposition ----
    float m[HD];
    {
        half2_t axf[5];
        #pragma unroll
        for (int j = 0; j < 5; ++j) {
            float a0 = xf[base + (2*j)*PIX] * ha;
            float a1 = xf[base + (2*j+1)*PIX] * ha;
            axf[j] = __builtin_bit_cast(half2_t, pk(a0, a1));
        }
        float h[C2];
        #pragma unroll
        for (int o = 0; o < C2; ++o) {
            float a = wsf[DB1 + o];
            #pragma unroll
            for (int j = 0; j < 5; ++j) a = dot2(wsl[DW1 + o*10 + j], axf[j], a);
            #pragma unroll
            for (int j = 0; j < 5; ++j) a = dot2(wsl[DW1 + o*10 + 5 + j], axh[j], a);
            h[o] = fmaxf(a, 0.f);
        }
        half2_t hp[10];
        #pragma unroll
        for (int j = 0; j < 10; ++j)
            hp[j] = __builtin_bit_cast(half2_t, pk(h[2*j], h[2*j+1]));
        #pragma unroll
        for (int o = 0; o < HD; ++o) {
            float a = wsf[DB2 + o];
            #pragma unroll
            for (int j = 0; j < 10; ++j) a = dot2(wsl[DW2 + o*10 + j], hp[j], a);
            m[o] = fmaxf(a, 0.f);
        }
    }

    // ---- composition ----
    {
        float pre[C2];
        #pragma unroll
        for (int o = 0; o < C2; ++o) {
            float a = wsf[CB1 + o];
            #pragma unroll
            for (int j = 0; j < 5; ++j) a = dot2(wsl[CW1 + o*10 + j], axh[j], a);
            pre[o] = a;
        }
        const int pstart = half ? 4 : 0;
        const int nparts = half ? 2 : 4;
        #pragma unroll
        for (int i = 0; i < 4; ++i) {
            if (i < nparts) {                     // wave-uniform guard
                half2_t xpp[5];
                #pragma unroll
                for (int j = 0; j < 5; ++j) {
                    float a0 = xp[(pstart + i) * CHW + base + (2*j)*PIX] * catt;
                    float a1 = xp[(pstart + i) * CHW + base + (2*j+1)*PIX] * catt;
                    xpp[j] = __builtin_bit_cast(half2_t, pk(a0, a1));
                }
                float h[C2];
                #pragma unroll
                for (int o = 0; o < C2; ++o) {
                    float a = 0.f;
                    #pragma unroll
                    for (int j = 0; j < 5; ++j) a = dot2(wsl[CW1 + o*10 + 5 + j], xpp[j], a);
                    h[o] = fmaxf(a + pre[o], 0.f);
                }
                half2_t hp[10];
                #pragma unroll
                for (int j = 0; j < 10; ++j)
                    hp[j] = __builtin_bit_cast(half2_t, pk(h[2*j], h[2*j+1]));
                #pragma unroll
                for (int o = 0; o < HD; ++o) {
                    float a = wsf[CB2 + o];
                    #pragma unroll
                    for (int j = 0; j < 10; ++j) a = dot2(wsl[CW2 + o*10 + j], hp[j], a);
                    m[o] += fmaxf(a, 0.f);
                }
            }
        }
    }

    // ---- GRU ----
    half2_t mp[5];
    #pragma unroll
    for (int j = 0; j < 5; ++j)
        mp[j] = __builtin_bit_cast(half2_t, pk(m[2*j], m[2*j+1]));
    float g[C2];
    #pragma unroll
    for (int o = 0; o < C2; ++o) {
        float a = wsf[BGo + o];
        #pragma unroll
        for (int j = 0; j < 5; ++j) a = dot2(wsl[WGo + o*10 + j], mp[j], a);
        #pragma unroll
        for (int j = 0; j < 5; ++j) a = dot2(wsl[WGo + o*10 + 5 + j], axh[j], a);
        g[o] = sigm(a);
    }
    half2_t rhp[5];
    #pragma unroll
    for (int j = 0; j < 5; ++j)
        rhp[j] = __builtin_bit_cast(half2_t, pk(g[2*j] * vxh[2*j], g[2*j+1] * vxh[2*j+1]));
    #pragma unroll
    for (int o = 0; o < HD; ++o) {
        float a = wsf[BCo + o];
        #pragma unroll
        for (int j = 0; j < 5; ++j) a = dot2(wsl[WCo + o*10 + j], mp[j], a);
        #pragma unroll
        for (int j = 0; j < 5; ++j) a = dot2(wsl[WCo + o*10 + 5 + j], rhp[j], a);
        float c = tanh_fast(a);
        float u = g[HD + o];
        outh[base + o*PIX] = fmaf(u, c - vxh[o], vxh[o]);
    }
}

// ---------------- fallback: proven r7 f32 kernel (used if ws too small) ----------------
__global__ __launch_bounds__(256) void half_kernel_f32(
    const float* __restrict__ xf, const float* __restrict__ xh, const float* __restrict__ xp,
    const float* __restrict__ h_att, const float* __restrict__ p_att,
    const float* __restrict__ dW1, const float* __restrict__ dbn1,
    const float* __restrict__ dW2, const float* __restrict__ dbn2,
    const float* __restrict__ uW1, const float* __restrict__ ubn1,
    const float* __restrict__ uW2, const float* __restrict__ ubn2,
    const float* __restrict__ lW1, const float* __restrict__ lbn1,
    const float* __restrict__ lW2, const float* __restrict__ lbn2,
    const float* __restrict__ guWg, const float* __restrict__ gubg,
    const float* __restrict__ guWc, const float* __restrict__ gubc,
    const float* __restrict__ glWg, const float* __restrict__ glbg,
    const float* __restrict__ glWc, const float* __restrict__ glbc,
    float* __restrict__ out)
{
    const int bid  = blockIdx.x;
    const int half = bid & 1;
    const int bx   = bid >> 1;
    const int b    = bx / BPB;
    const int s    = (bx - b * BPB) * 256 + threadIdx.x;
    const int base  = b * (HD*PIX) + s;
    const int abase = b * PIX + s;

    const float* Wc1  = half ? lW1  : uW1;
    const float* cbn1 = half ? lbn1 : ubn1;
    const float* Wc2  = half ? lW2  : uW2;
    const float* cbn2 = half ? lbn2 : ubn2;
    const float* Wg = half ? glWg : guWg;
    const float* bg = half ? glbg : gubg;
    const float* Wc = half ? glWc : guWc;
    const float* bc = half ? glbc : gubc;

    const float* xhh = xh + half * CHW;
    float* outh = out + half * CHW;

    float vxh[HD];
    #pragma unroll
    for (int c = 0; c < HD; ++c) vxh[c] = xhh[base + c*PIX];

    const float ha = h_att[(1 + half) * NPIX + abase];
    float catt = 0.f;
    {
        const int mstart = half ? 5 : 1;
        const int natt   = half ? 2 : 4;
        #pragma unroll
        for (int j = 0; j < 4; ++j)
            if (j < natt) catt += p_att[(mstart + j) * NPIX + abase];
    }

    float m[HD];
    {
        float xfha[HD];
        #pragma unroll
        for (int c = 0; c < HD; ++c) xfha[c] = xf[base + c*PIX] * ha;
        float h[C2];
        #pragma unroll
        for (int o = 0; o < C2; ++o) {
            float a = 0.f;
            #pragma unroll
            for (int k = 0; k < HD; ++k) a = fmaf(dW1[o*C2 + k], xfha[k], a);
            #pragma unroll
            for (int k = 0; k < HD; ++k) a = fmaf(dW1[o*C2 + HD + k], vxh[k], a);
            float sc = dbn1[o] * rsq_fast(dbn1[3*C2 + o] + EPSB);
            float tr = dbn1[C2 + o] - sc * dbn1[2*C2 + o];
            h[o] = fmaxf(fmaf(a, sc, tr), 0.f);
        }
        #pragma unroll
        for (int o = 0; o < HD; ++o) {
            float a = 0.f;
            #pragma unroll
            for (int k = 0; k < C2; ++k) a = fmaf(dW2[o*C2 + k], h[k], a);
            float sc = dbn2[o] * rsq_fast(dbn2[3*HD + o] + EPSB);
            float tr = dbn2[HD + o] - sc * dbn2[2*HD + o];
            m[o] = fmaxf(fmaf(a, sc, tr), 0.f);
        }
    }
    {
        float s1[C2], s2[HD], t2[HD];
        #pragma unroll
        for (int o = 0; o < C2; ++o)
            s1[o] = cbn1[o] * rsq_fast(cbn1[3*C2 + o] + EPSB);
        #pragma unroll
        for (int o = 0; o < HD; ++o) {
            s2[o] = cbn2[o] * rsq_fast(cbn2[3*HD + o] + EPSB);
            t2[o] = cbn2[HD + o] - s2[o] * cbn2[2*HD + o];
        }
        float pre[C2];
        #pragma unroll
        for (int o = 0; o < C2; ++o) {
            float a = 0.f;
            #pragma unroll
            for (int k = 0; k < HD; ++k) a = fmaf(Wc1[o*C2 + k], vxh[k], a);
            float t1 = cbn1[C2 + o] - s1[o] * cbn1[2*C2 + o];
            pre[o] = fmaf(a, s1[o], t1);
        }
        const int pstart = half ? 4 : 0;
        const int nparts = half ? 2 : 4;
        #pragma unroll
        for (int i = 0; i < 4; ++i) {
            if (i < nparts) {
                float xpi[HD];
                #pragma unroll
                for (int c = 0; c < HD; ++c)
                    xpi[c] = xp[(pstart + i) * CHW + base + c*PIX];
                float h[C2];
                #pragma unroll
                for (int o = 0; o < C2; ++o) {
                    float a = 0.f;
                    #pragma unroll
                    for (int k = 0; k < HD; ++k) a = fmaf(Wc1[o*C2 + HD + k], xpi[k], a);
                    h[o] = fmaxf(fmaf(a, catt * s1[o], pre[o]), 0.f);
                }
                #pragma unroll
                for (int o = 0; o < HD; ++o) {
                    float a = 0.f;
                    #pragma unroll
                    for (int k = 0; k < C2; ++k) a = fmaf(Wc2[o*C2 + k], h[k], a);
                    m[o] += fmaxf(fmaf(a, s2[o], t2[o]), 0.f);
                }
            }
        }
    }
    float g[C2];
    #pragma unroll
    for (int o = 0; o < C2; ++o) {
        float a = bg[o];
        #pragma unroll
        for (int k = 0; k < HD; ++k) a = fmaf(Wg[o*C2 + k], m[k], a);
        #pragma unroll
        for (int k = 0; k < HD; ++k) a = fmaf(Wg[o*C2 + HD + k], vxh[k], a);
        g[o] = sigm(a);
    }
    float rh[HD];
    #pragma unroll
    for (int k = 0; k < HD; ++k) rh[k] = g[k] * vxh[k];
    #pragma unroll
    for (int o = 0; o < HD; ++o) {
        float a = bc[o];
        #pragma unroll
        for (int k = 0; k < HD; ++k) a = fmaf(Wc[o*C2 + k], m[k], a);
        #pragma unroll
        for (int k = 0; k < HD; ++k) a = fmaf(Wc[o*C2 + HD + k], rh[k], a);
        float c = tanh_fast(a);
        float u = g[HD + o];
        outh[base + o*PIX] = fmaf(u, c - vxh[o], vxh[o]);
    }
}

extern "C" void kernel_launch(void* const* d_in, const int* in_sizes, int n_in,
                              void* d_out, int out_size, void* d_ws, size_t ws_size,
                              hipStream_t stream) {
    const float* xf    = (const float*)d_in[0];
    const float* xh    = (const float*)d_in[1];
    const float* xp    = (const float*)d_in[2];
    const float* h_att = (const float*)d_in[3];
    const float* p_att = (const float*)d_in[4];
    const float* dW1   = (const float*)d_in[5];
    const float* dbn1  = (const float*)d_in[6];
    const float* dW2   = (const float*)d_in[7];
    const float* dbn2  = (const float*)d_in[8];
    const float* uW1   = (const float*)d_in[9];
    const float* ubn1  = (const float*)d_in[10];
    const float* uW2   = (const float*)d_in[11];
    const float* ubn2  = (const float*)d_in[12];
    const float* lW1   = (const float*)d_in[13];
    const float* lbn1  = (const float*)d_in[14];
    const float* lW2   = (const float*)d_in[15];
    const float* lbn2  = (const float*)d_in[16];
    const float* guWg  = (const float*)d_in[17];
    const float* gubg  = (const float*)d_in[18];
    const float* guWc  = (const float*)d_in[19];
    const float* gubc  = (const float*)d_in[20];
    const float* glWg  = (const float*)d_in[21];
    const float* glbg  = (const float*)d_in[22];
    const float* glWc  = (const float*)d_in[23];
    const float* glbc  = (const float*)d_in[24];

    dim3 grid(NBLK), block(256);
    if (ws_size >= (size_t)NBLK * SLICE * 4) {
        half_kernel_f16<<<grid, block, 0, stream>>>(
            xf, xh, xp, h_att, p_att,
            dW1, dbn1, dW2, dbn2,
            uW1, ubn1, uW2, ubn2,
            lW1, lbn1, lW2, lbn2,
            guWg, gubg, guWc, gubc,
            glWg, glbg, glWc, glbc,
            (uint*)d_ws, (float*)d_out);
    } else {
        half_kernel_f32<<<grid, block, 0, stream>>>(
            xf, xh, xp, h_att, p_att,
            dW1, dbn1, dW2, dbn2,
            uW1, ubn1, uW2, ubn2,
            lW1, lbn1, lW2, lbn2,
            guWg, gubg, guWc, gubc,
            glWg, glbg, glWc, glbc,
            (float*)d_out);
    }
}

// Round 13
// 109.825 us; speedup vs baseline: 1.6759x; 1.2415x over previous
//
#include <hip/hip_runtime.h>

#define HD 10
#define C2 20
#define PIX (192*192)
#define NB 8
#define NPIX (NB*PIX)
#define CHW (NB*HD*PIX)
#define EPSB 1e-5f
#define BPB (PIX/256)        // blocks per (batch,half) image = 144

__device__ __forceinline__ float rsq_fast(float x) {
    return __builtin_amdgcn_rsqf(x);        // single v_rsq_f32 (BN vars in [0.5,1.5])
}
__device__ __forceinline__ float sigm(float x) {
    return __builtin_amdgcn_rcpf(1.0f + __expf(-x));
}
__device__ __forceinline__ float tanh_fast(float x) {
    return 1.0f - 2.0f * __builtin_amdgcn_rcpf(1.0f + __expf(2.0f * x));
}

// r7 structure with MINIMIZED CODE FOOTPRINT (I$-thrash hypothesis):
// the part loop is a RUNTIME loop (one 450-instr body instead of four),
// p_att sum rolled. Register arrays keep compile-time indices everywhere
// (loop index only feeds addresses). Est. ~17 KB body vs r7's ~28 KB,
// against a 32 KB SQC I$ shared by neighboring CUs.
__global__ __launch_bounds__(256) void half_kernel(
    const float* __restrict__ xf, const float* __restrict__ xh, const float* __restrict__ xp,
    const float* __restrict__ h_att, const float* __restrict__ p_att,
    const float* __restrict__ dW1, const float* __restrict__ dbn1,
    const float* __restrict__ dW2, const float* __restrict__ dbn2,
    const float* __restrict__ uW1, const float* __restrict__ ubn1,
    const float* __restrict__ uW2, const float* __restrict__ ubn2,
    const float* __restrict__ lW1, const float* __restrict__ lbn1,
    const float* __restrict__ lW2, const float* __restrict__ lbn2,
    const float* __restrict__ guWg, const float* __restrict__ gubg,
    const float* __restrict__ guWc, const float* __restrict__ gubc,
    const float* __restrict__ glWg, const float* __restrict__ glbg,
    const float* __restrict__ glWc, const float* __restrict__ glbc,
    float* __restrict__ out)
{
    const int bid  = blockIdx.x;
    const int half = bid & 1;                    // interleaved for load balance
    const int bx   = bid >> 1;
    const int b    = bx / BPB;                   // uniform per block
    const int s    = (bx - b * BPB) * 256 + threadIdx.x;
    const int base  = b * (HD*PIX) + s;          // [B,HD,P] tensors: + c*PIX
    const int abase = b * PIX + s;               // [*,B,1,P] attention maps

    // wave-uniform weight/BN pointers (selected by uniform `half`)
    const float* Wc1  = half ? lW1  : uW1;
    const float* cbn1 = half ? lbn1 : ubn1;
    const float* Wc2  = half ? lW2  : uW2;
    const float* cbn2 = half ? lbn2 : ubn2;
    const float* Wg = half ? glWg : guWg;
    const float* bg = half ? glbg : gubg;
    const float* Wc = half ? glWc : guWc;
    const float* bc = half ? glbc : gubc;

    const float* xhh = xh + half * CHW;
    float* outh = out + half * CHW;

    float vxh[HD];
    #pragma unroll
    for (int c = 0; c < HD; ++c) vxh[c] = xhh[base + c*PIX];

    const float ha = h_att[(1 + half) * NPIX + abase];
    float catt = 0.f;
    {
        const int mstart = half ? 5 : 1;
        const int natt   = half ? 2 : 4;
        #pragma unroll 1
        for (int j = 0; j < natt; ++j)           // runtime loop: code size
            catt += p_att[(mstart + j) * NPIX + abase];
    }

    // ---- decomposition block -> message accumulator m (BN applied inline) ----
    float m[HD];
    {
        float xfha[HD];
        #pragma unroll
        for (int c = 0; c < HD; ++c) xfha[c] = xf[base + c*PIX] * ha;
        float h[C2];
        #pragma unroll
        for (int o = 0; o < C2; ++o) {
            float a = 0.f;
            #pragma unroll
            for (int k = 0; k < HD; ++k) a = fmaf(dW1[o*C2 + k], xfha[k], a);
            #pragma unroll
            for (int k = 0; k < HD; ++k) a = fmaf(dW1[o*C2 + HD + k], vxh[k], a);
            float sc = dbn1[o] * rsq_fast(dbn1[3*C2 + o] + EPSB);
            float tr = dbn1[C2 + o] - sc * dbn1[2*C2 + o];
            h[o] = fmaxf(fmaf(a, sc, tr), 0.f);
        }
        #pragma unroll
        for (int o = 0; o < HD; ++o) {
            float a = 0.f;
            #pragma unroll
            for (int k = 0; k < C2; ++k) a = fmaf(dW2[o*C2 + k], h[k], a);
            float sc = dbn2[o] * rsq_fast(dbn2[3*HD + o] + EPSB);
            float tr = dbn2[HD + o] - sc * dbn2[2*HD + o];
            m[o] = fmaxf(fmaf(a, sc, tr), 0.f);
        }
    }

    // ---- composition blocks (RUNTIME part loop: one body in I$, not four) ----
    {
        float s1c[C2], s2[HD], t2[HD];           // BN constants (reused across parts)
        float pre[C2];
        #pragma unroll
        for (int o = 0; o < C2; ++o) {
            float s1 = cbn1[o] * rsq_fast(cbn1[3*C2 + o] + EPSB);
            float a = 0.f;
            #pragma unroll
            for (int k = 0; k < HD; ++k) a = fmaf(Wc1[o*C2 + k], vxh[k], a);
            float t1 = cbn1[C2 + o] - s1 * cbn1[2*C2 + o];
            pre[o] = fmaf(a, s1, t1);
            s1c[o] = s1 * catt;                  // catt folded into part-conv scale
        }
        #pragma unroll
        for (int o = 0; o < HD; ++o) {
            s2[o] = cbn2[o] * rsq_fast(cbn2[3*HD + o] + EPSB);
            t2[o] = cbn2[HD + o] - s2[o] * cbn2[2*HD + o];
        }
        const int pstart = half ? 4 : 0;
        const int pend   = half ? 6 : 4;
        #pragma unroll 1
        for (int i = pstart; i < pend; ++i) {    // runtime loop: i feeds ADDRESSES only
            float xpi[HD];
            #pragma unroll
            for (int c = 0; c < HD; ++c)
                xpi[c] = xp[i * CHW + base + c*PIX];
            float h[C2];
            #pragma unroll
            for (int o = 0; o < C2; ++o) {
                float a = 0.f;
                #pragma unroll
                for (int k = 0; k < HD; ++k) a = fmaf(Wc1[o*C2 + HD + k], xpi[k], a);
                h[o] = fmaxf(fmaf(a, s1c[o], pre[o]), 0.f);
            }
            #pragma unroll
            for (int o = 0; o < HD; ++o) {
                float a = 0.f;
                #pragma unroll
                for (int k = 0; k < C2; ++k) a = fmaf(Wc2[o*C2 + k], h[k], a);
                m[o] += fmaxf(fmaf(a, s2[o], t2[o]), 0.f);
            }
        }
    }

    // ---- GRU ----
    float g[C2];
    #pragma unroll
    for (int o = 0; o < C2; ++o) {
        float a = bg[o];
        #pragma unroll
        for (int k = 0; k < HD; ++k) a = fmaf(Wg[o*C2 + k], m[k], a);
        #pragma unroll
        for (int k = 0; k < HD; ++k) a = fmaf(Wg[o*C2 + HD + k], vxh[k], a);
        g[o] = sigm(a);
    }
    float rh[HD];
    #pragma unroll
    for (int k = 0; k < HD; ++k) rh[k] = g[k] * vxh[k];
    #pragma unroll
    for (int o = 0; o < HD; ++o) {
        float a = bc[o];
        #pragma unroll
        for (int k = 0; k < HD; ++k) a = fmaf(Wc[o*C2 + k], m[k], a);
        #pragma unroll
        for (int k = 0; k < HD; ++k) a = fmaf(Wc[o*C2 + HD + k], rh[k], a);
        float c = tanh_fast(a);
        float u = g[HD + o];
        outh[base + o*PIX] = fmaf(u, c - vxh[o], vxh[o]);   // (1-u)*h + u*c
    }
}

extern "C" void kernel_launch(void* const* d_in, const int* in_sizes, int n_in,
                              void* d_out, int out_size, void* d_ws, size_t ws_size,
                              hipStream_t stream) {
    const float* xf    = (const float*)d_in[0];
    const float* xh    = (const float*)d_in[1];
    const float* xp    = (const float*)d_in[2];
    const float* h_att = (const float*)d_in[3];
    const float* p_att = (const float*)d_in[4];
    const float* dW1   = (const float*)d_in[5];
    const float* dbn1  = (const float*)d_in[6];
    const float* dW2   = (const float*)d_in[7];
    const float* dbn2  = (const float*)d_in[8];
    const float* uW1   = (const float*)d_in[9];
    const float* ubn1  = (const float*)d_in[10];
    const float* uW2   = (const float*)d_in[11];
    const float* ubn2  = (const float*)d_in[12];
    const float* lW1   = (const float*)d_in[13];
    const float* lbn1  = (const float*)d_in[14];
    const float* lW2   = (const float*)d_in[15];
    const float* lbn2  = (const float*)d_in[16];
    const float* guWg  = (const float*)d_in[17];
    const float* gubg  = (const float*)d_in[18];
    const float* guWc  = (const float*)d_in[19];
    const float* gubc  = (const float*)d_in[20];
    const float* glWg  = (const float*)d_in[21];
    const float* glbg  = (const float*)d_in[22];
    const float* glWc  = (const float*)d_in[23];
    const float* glbc  = (const float*)d_in[24];

    dim3 grid((NPIX / 256) * 2), block(256);
    half_kernel<<<grid, block, 0, stream>>>(
        xf, xh, xp, h_att, p_att,
        dW1, dbn1, dW2, dbn2,
        uW1, ubn1, uW2, ubn2,
        lW1, lbn1, lW2, lbn2,
        guWg, gubg, guWc, gubc,
        glWg, glbg, glWc, glbc,
        (float*)d_out);
}